// Round 11
// baseline (74.749 us; speedup 1.0000x reference)
//
#include <hip/hip_runtime.h>

#define NPTS 16384
#define KS   16                  // stored bf16 k-slots per point (32 B)
#define BT   256                 // 4 waves per block
#define BROWS 128                // rows per block: 4 waves x 1 32-row tile
#define TSPLIT 5                 // 5 blocks/CU exactly (grid 128*5*2 = 1280)
#define TTILES 512               // total 32-target tiles (16384/32)

typedef __attribute__((ext_vector_type(8)))  short bf16x8;
typedef __attribute__((ext_vector_type(16))) float f32x16;
typedef __attribute__((ext_vector_type(8)))  unsigned short ushort8;

__device__ __forceinline__ unsigned short btrunc(float f) {
    return (unsigned short)(__float_as_uint(f) >> 16);
}
__device__ __forceinline__ float btruncf(float f) {
    return __uint_as_float(__float_as_uint(f) & 0xFFFF0000u);
}

// A-role (source rows):  [-2xh, -2xl, -2xh, -2yh, -2yl, -2yh, -2zh, -2zl, -2zh, 1, 1, 0...]
// B-role (target cols):  [ xh ,  xh ,  xl ,  yh ,  yh ,  yl ,  zh ,  zh ,  zl , qh, ql, 0...]
// A(s).B(t) = -2 s.t + |t|^2   (lo*lo cross terms dropped, ~2^-16 relative)
__global__ void chamfer_pack(const float* __restrict__ s,
                             const float* __restrict__ t,
                             unsigned short* __restrict__ Apack,
                             unsigned short* __restrict__ Bpack,
                             float* __restrict__ sq,
                             unsigned* __restrict__ outinit)
{
    int i = blockIdx.x * blockDim.x + threadIdx.x;
    if (i >= 2 * NPTS) return;
    outinit[i] = 0x7F7F7F7Fu;            // huge positive float; out_size == 2*NPTS
    int cloud = i >> 14;
    int p = i & (NPTS - 1);
    const float* base = cloud ? t : s;
    float x = base[3 * p], y = base[3 * p + 1], z = base[3 * p + 2];

    float xh = btruncf(x), yh = btruncf(y), zh = btruncf(z);
    float xl = x - xh, yl = y - yh, zl = z - zh;
    float q = x * x + y * y + z * z;
    float qh = btruncf(q), ql = q - qh;

    const unsigned short one = btrunc(1.0f);
    ushort8 A0 = { btrunc(-2.f * xh), btrunc(-2.f * xl), btrunc(-2.f * xh),
                   btrunc(-2.f * yh), btrunc(-2.f * yl), btrunc(-2.f * yh),
                   btrunc(-2.f * zh), btrunc(-2.f * zl) };
    ushort8 A1 = { btrunc(-2.f * zh), one, one, 0, 0, 0, 0, 0 };
    ushort8 B0 = { btrunc(xh), btrunc(xh), btrunc(xl),
                   btrunc(yh), btrunc(yh), btrunc(yl),
                   btrunc(zh), btrunc(zh) };
    ushort8 B1 = { btrunc(zl), btrunc(qh), btrunc(ql), 0, 0, 0, 0, 0 };

    *(ushort8*)(Apack + (size_t)i * KS)     = A0;
    *(ushort8*)(Apack + (size_t)i * KS + 8) = A1;
    *(ushort8*)(Bpack + (size_t)i * KS)     = B0;
    *(ushort8*)(Bpack + (size_t)i * KS + 8) = B1;
    sq[i] = q;
}

// grid = (128, 5, 2) = 1280 blocks = 5 blocks/CU = 5 waves/SIMD (bounds 256,5: 102-reg cap).
// Minimal per-wave state (~92 unified regs incl. AGPR block): single c per round,
// 1-deep prefetch. Block y sweeps tiles [y*512/5, (y+1)*512/5).
__global__ __launch_bounds__(BT, 5)
void chamfer_mfma(const unsigned short* __restrict__ Apack,
                  const unsigned short* __restrict__ Bpack,
                  const float* __restrict__ sq,
                  unsigned* __restrict__ out)
{
    const int dir = blockIdx.z;
    const unsigned short* A = Apack + (size_t)(dir ? NPTS : 0) * KS;
    const unsigned short* B = Bpack + (size_t)(dir ? 0 : NPTS) * KS;
    const float* s2 = sq + (dir ? NPTS : 0);
    unsigned* o = out + dir * NPTS;

    const int lane = threadIdx.x & 63;
    const int wv   = threadIdx.x >> 6;
    const int n32  = lane & 31;
    const int kh   = lane >> 5;         // k-slice half (0: k0..7, 1: k8..15)

    const int rbase = blockIdx.x * BROWS + wv * 32;
    const bf16x8 a0 = *(const bf16x8*)(A + (size_t)(rbase + n32) * KS + kh * 8);

    f32x16 mn, zc;
#pragma unroll
    for (int r = 0; r < 16; ++r) { mn[r] = 1e30f; zc[r] = 0.0f; }
    asm volatile("" : "+v"(zc));        // opaque: keep C-block pinned, no remat

    const int ts = (int)((blockIdx.y * TTILES) / TSPLIT);
    const int te = (int)(((blockIdx.y + 1) * TTILES) / TSPLIT);

    const unsigned short* Bl = B + (size_t)n32 * KS + kh * 8;
#define BTILE(t) (*(const bf16x8*)(Bl + (size_t)(t) * 32 * KS))

    bf16x8 b0 = BTILE(ts);
#pragma unroll 2
    for (int t = ts; t < te; ++t) {
        f32x16 c = __builtin_amdgcn_mfma_f32_32x32x16_bf16(a0, b0, zc, 0, 0, 0);
        int tn = (t + 1 < te) ? t + 1 : te - 1;
        bf16x8 bn = BTILE(tn);           // issue next load before consuming c
#pragma unroll
        for (int k = 0; k < 16; ++k) mn[k] = fminf(mn[k], c[k]);
        b0 = bn;
    }
#undef BTILE

    // column reduce across the 32 lanes of each half-wave group
#pragma unroll
    for (int r = 0; r < 16; ++r) {
        float v0 = mn[r];
        v0 = fminf(v0, __shfl_xor(v0, 1, 32));
        v0 = fminf(v0, __shfl_xor(v0, 2, 32));
        v0 = fminf(v0, __shfl_xor(v0, 4, 32));
        v0 = fminf(v0, __shfl_xor(v0, 8, 32));
        v0 = fminf(v0, __shfl_xor(v0, 16, 32));
        mn[r] = v0;
    }

    if (n32 == 0) {
        // C/D map (32x32, r2/r3-verified): col = lane&31, row = (r&3) + 8*(r>>2) + 4*kh
#pragma unroll
        for (int r = 0; r < 16; ++r) {
            int row = rbase + (r & 3) + 8 * (r >> 2) + 4 * kh;
            float d = fmaxf(mn[r] + s2[row], 0.0f);
            atomicMin(&o[row], __float_as_uint(d));
        }
    }
}

extern "C" void kernel_launch(void* const* d_in, const int* in_sizes, int n_in,
                              void* d_out, int out_size, void* d_ws, size_t ws_size,
                              hipStream_t stream) {
    const float* s = (const float*)d_in[0];
    const float* t = (const float*)d_in[1];

    unsigned short* Apack = (unsigned short*)d_ws;                 // 1 MB
    unsigned short* Bpack = Apack + (size_t)2 * NPTS * KS;         // 1 MB
    float* sq = (float*)(Bpack + (size_t)2 * NPTS * KS);           // 128 KB

    chamfer_pack<<<(2 * NPTS + BT - 1) / BT, BT, 0, stream>>>(
        s, t, Apack, Bpack, sq, (unsigned*)d_out);

    dim3 grid(NPTS / BROWS, TSPLIT, 2);
    chamfer_mfma<<<grid, BT, 0, stream>>>(Apack, Bpack, sq, (unsigned*)d_out);
}

// Round 12
// 35.073 us; speedup vs baseline: 2.1312x; 2.1312x over previous
//
#include <hip/hip_runtime.h>

#define NPTS 16384
#define KS   16                  // stored bf16 k-slots per point (32 B)
#define BT   256                 // 4 waves per block
#define BROWS 128                // rows per block: 4 waves x 1 32-row tile
#define TSPLIT 4
#define SWEEP (NPTS / TSPLIT)    // 4096 targets per block sweep
#define NTILE (SWEEP / 32)       // 128 32-target tiles
#define NP (NTILE / 2)           // 64 2-tile phases

typedef __attribute__((ext_vector_type(8)))  short bf16x8;
typedef __attribute__((ext_vector_type(16))) float f32x16;
typedef __attribute__((ext_vector_type(8)))  unsigned short ushort8;

__device__ __forceinline__ unsigned short btrunc(float f) {
    return (unsigned short)(__float_as_uint(f) >> 16);
}
__device__ __forceinline__ float btruncf(float f) {
    return __uint_as_float(__float_as_uint(f) & 0xFFFF0000u);
}

// A-role (source rows):  [-2xh, -2xl, -2xh, -2yh, -2yl, -2yh, -2zh, -2zl, -2zh, 1, 1, 0...]
// B-role (target cols):  [ xh ,  xh ,  xl ,  yh ,  yh ,  yl ,  zh ,  zh ,  zl , qh, ql, 0...]
// A(s).B(t) = -2 s.t + |t|^2   (lo*lo cross terms dropped, ~2^-16 relative)
__global__ void chamfer_pack(const float* __restrict__ s,
                             const float* __restrict__ t,
                             unsigned short* __restrict__ Apack,
                             unsigned short* __restrict__ Bpack,
                             float* __restrict__ sq,
                             unsigned* __restrict__ outinit)
{
    int i = blockIdx.x * blockDim.x + threadIdx.x;
    if (i >= 2 * NPTS) return;
    outinit[i] = 0x7F7F7F7Fu;            // huge positive float; out_size == 2*NPTS
    int cloud = i >> 14;
    int p = i & (NPTS - 1);
    const float* base = cloud ? t : s;
    float x = base[3 * p], y = base[3 * p + 1], z = base[3 * p + 2];

    float xh = btruncf(x), yh = btruncf(y), zh = btruncf(z);
    float xl = x - xh, yl = y - yh, zl = z - zh;
    float q = x * x + y * y + z * z;
    float qh = btruncf(q), ql = q - qh;

    const unsigned short one = btrunc(1.0f);
    ushort8 A0 = { btrunc(-2.f * xh), btrunc(-2.f * xl), btrunc(-2.f * xh),
                   btrunc(-2.f * yh), btrunc(-2.f * yl), btrunc(-2.f * yh),
                   btrunc(-2.f * zh), btrunc(-2.f * zl) };
    ushort8 A1 = { btrunc(-2.f * zh), one, one, 0, 0, 0, 0, 0 };
    ushort8 B0 = { btrunc(xh), btrunc(xh), btrunc(xl),
                   btrunc(yh), btrunc(yh), btrunc(yl),
                   btrunc(zh), btrunc(zh) };
    ushort8 B1 = { btrunc(zl), btrunc(qh), btrunc(ql), 0, 0, 0, 0, 0 };

    *(ushort8*)(Apack + (size_t)i * KS)     = A0;
    *(ushort8*)(Apack + (size_t)i * KS + 8) = A1;
    *(ushort8*)(Bpack + (size_t)i * KS)     = B0;
    *(ushort8*)(Bpack + (size_t)i * KS + 8) = B1;
    sq[i] = q;
}

// grid = (128, 4, 2) = 1024 blocks = 4/CU = 4 waves/SIMD.
// Inline-asm MFMA: D forced into arch VGPRs ("=&v"), C = inline 0 (no zc block),
// s_nop x3 (24 cyc) fences the MFMA->VALU RAW hazard (r4 lesson), sched_barrier(0)
// pins the min3 block between fences (rule 18: VALU crosses volatile asm freely).
// This kills the AGPR accvgpr-bounce that inflated VALU 2-4x in r3..r11.
__global__ __launch_bounds__(BT, 4)
void chamfer_mfma(const unsigned short* __restrict__ Apack,
                  const unsigned short* __restrict__ Bpack,
                  const float* __restrict__ sq,
                  unsigned* __restrict__ out)
{
    const int dir = blockIdx.z;
    const unsigned short* A = Apack + (size_t)(dir ? NPTS : 0) * KS;
    const unsigned short* B = Bpack + (size_t)(dir ? 0 : NPTS) * KS;
    const float* s2 = sq + (dir ? NPTS : 0);
    unsigned* o = out + dir * NPTS;

    const int lane = threadIdx.x & 63;
    const int wv   = threadIdx.x >> 6;
    const int n32  = lane & 31;
    const int kh   = lane >> 5;         // k-slice half (0: k0..7, 1: k8..15)

    const int rbase = blockIdx.x * BROWS + wv * 32;
    const bf16x8 a0 = *(const bf16x8*)(A + (size_t)(rbase + n32) * KS + kh * 8);

    f32x16 mn;
#pragma unroll
    for (int r = 0; r < 16; ++r) mn[r] = 1e30f;

    const unsigned short* Bl = B + (size_t)(blockIdx.y * SWEEP + n32) * KS + kh * 8;
#define BTILE(t) (*(const bf16x8*)(Bl + (size_t)(t) * 32 * KS))

    // One 2-tile phase: issue 2 MFMAs (arch-VGPR dest, C=0), hazard nops,
    // then 16 v_min3 pinned between sched_barriers.
#define PHASE(bb0, bb1)                                                          \
    {                                                                            \
        f32x16 c0, c1;                                                           \
        asm volatile("v_mfma_f32_32x32x16_bf16 %0, %2, %3, 0\n\t"                \
                     "v_mfma_f32_32x32x16_bf16 %1, %2, %4, 0\n\t"                \
                     "s_nop 7\n\ts_nop 7\n\ts_nop 7"                             \
                     : "=&v"(c0), "=&v"(c1)                                      \
                     : "v"(a0), "v"(bb0), "v"(bb1));                             \
        __builtin_amdgcn_sched_barrier(0);                                       \
        _Pragma("unroll")                                                        \
        for (int k = 0; k < 16; ++k)                                             \
            mn[k] = fminf(fminf(mn[k], c0[k]), c1[k]);  /* -> v_min3_f32 */      \
        __builtin_amdgcn_sched_barrier(0);                                       \
        asm volatile("" : "+v"(mn));   /* pin mn in arch VGPRs, no AGPR bounce */\
    }

    bf16x8 x0 = BTILE(0), x1 = BTILE(1);
    bf16x8 y0 = BTILE(2), y1 = BTILE(3);

#pragma unroll 1
    for (int p = 0; p < NP; p += 2) {
        int ta = (2 * p + 4 < NTILE) ? 2 * p + 4 : NTILE - 2;   // clamped prefetch
        int tb = (2 * p + 6 < NTILE) ? 2 * p + 6 : NTILE - 2;
        bf16x8 nx0 = BTILE(ta), nx1 = BTILE(ta + 1);
        PHASE(x0, x1);
        x0 = nx0; x1 = nx1;
        bf16x8 ny0 = BTILE(tb), ny1 = BTILE(tb + 1);
        PHASE(y0, y1);
        y0 = ny0; y1 = ny1;
    }
#undef PHASE
#undef BTILE

    // column reduce across the 32 lanes of each half-wave group
#pragma unroll
    for (int r = 0; r < 16; ++r) {
        float v0 = mn[r];
        v0 = fminf(v0, __shfl_xor(v0, 1, 32));
        v0 = fminf(v0, __shfl_xor(v0, 2, 32));
        v0 = fminf(v0, __shfl_xor(v0, 4, 32));
        v0 = fminf(v0, __shfl_xor(v0, 8, 32));
        v0 = fminf(v0, __shfl_xor(v0, 16, 32));
        mn[r] = v0;
    }

    if (n32 == 0) {
        // C/D map (32x32, r2/r3-verified): col = lane&31, row = (r&3) + 8*(r>>2) + 4*kh
#pragma unroll
        for (int r = 0; r < 16; ++r) {
            int row = rbase + (r & 3) + 8 * (r >> 2) + 4 * kh;
            float d = fmaxf(mn[r] + s2[row], 0.0f);
            atomicMin(&o[row], __float_as_uint(d));
        }
    }
}

extern "C" void kernel_launch(void* const* d_in, const int* in_sizes, int n_in,
                              void* d_out, int out_size, void* d_ws, size_t ws_size,
                              hipStream_t stream) {
    const float* s = (const float*)d_in[0];
    const float* t = (const float*)d_in[1];

    unsigned short* Apack = (unsigned short*)d_ws;                 // 1 MB
    unsigned short* Bpack = Apack + (size_t)2 * NPTS * KS;         // 1 MB
    float* sq = (float*)(Bpack + (size_t)2 * NPTS * KS);           // 128 KB

    chamfer_pack<<<(2 * NPTS + BT - 1) / BT, BT, 0, stream>>>(
        s, t, Apack, Bpack, sq, (unsigned*)d_out);

    dim3 grid(NPTS / BROWS, TSPLIT, 2);
    chamfer_mfma<<<grid, BT, 0, stream>>>(Apack, Bpack, sq, (unsigned*)d_out);
}